// Round 4
// baseline (404.661 us; speedup 1.0000x reference)
//
#include <hip/hip_runtime.h>
#include <math.h>

#define TT 288
#define VV 512
#define NC 32
#define NB 4

// ws layout (floats): Z | CV | IMP | COEF   (u lives in d_out between pass1/pass2)
static constexpr size_t Z_OFF    = 0;
static constexpr size_t CV_OFF   = (size_t)NB * NC * TT * VV;      // 18,874,368
static constexpr size_t IMP_OFF  = CV_OFF + (size_t)NB * TT * VV;  // +589,824
static constexpr size_t COEF_OFF = IMP_OFF + (size_t)NB * TT;      // +1,152
static constexpr size_t WS_NEED  = COEF_OFF + (size_t)NB * 8;      // ~77.9 MB

// ---------------- prep2: rolling CV (t-segmented) + impact scan + gate MLP ----
__global__ __launch_bounds__(256)
void prep2_kernel(const float* __restrict__ flow, const float* __restrict__ events,
                  const float* __restrict__ ef, const float* __restrict__ w1,
                  const float* __restrict__ b1, const float* __restrict__ w2,
                  const float* __restrict__ b2, float* __restrict__ ws) {
  __shared__ float sE[12][TT];
  float* CVp  = ws + CV_OFF;
  float* IMP  = ws + IMP_OFF;
  float* COEF = ws + COEF_OFF;
  const int blk = blockIdx.x, thr = threadIdx.x;

  if (blk < 32) {
    // CV: block = (b, tseg of 72, v-half); warm up 59 rows then slide
    const int b = blk >> 3, tseg = (blk >> 1) & 3, vh = blk & 1;
    const int v = vh * 256 + thr, ts = tseg * 72;
    const size_t base = (size_t)b * TT * VV + v;
    const int start = (ts >= 59) ? ts - 59 : 0;
    float s = 0.f, s2 = 0.f;
    for (int t = start; t < ts + 72; ++t) {
      float f = flow[base + (size_t)t * VV];
      s += f; s2 += f * f;
      if (t >= ts) {
        float cvv = 0.f;
        if (t >= 59) {
          float mean = s * (1.f / 60.f);
          float var  = (s2 - 60.f * mean * mean) * (1.f / 59.f);
          cvv = sqrtf(fmaxf(var, 0.f)) / (mean + 1e-6f);
        }
        CVp[base + (size_t)t * VV] = cvv;
      }
      if (t >= 59 && t - 59 >= start) {
        float fo = flow[base + (size_t)(t - 59) * VV];
        s -= fo; s2 -= fo * fo;
      }
    }
  } else {
    // impact: 12 threads = (e,b) parallel scans; gate MLP on threads 16..19
    if (thr < 12) {
      const int b = thr & 3, e = thr >> 2;
      const float r = (e == 0) ? expf(-1.f / 300.f) : (e == 1) ? expf(-1.f / 600.f) : expf(-1.f / 180.f);
      const float a = (e == 0) ? 0.3f : (e == 1) ? 0.5f : 0.2f;
      float c = 0.f;
#pragma unroll 4
      for (int t = TT - 1; t >= 0; --t) {
        c = events[((size_t)b * TT + t) * 3 + e] + r * c;
        sE[thr][t] = a * c;
      }
    } else if (thr >= 16 && thr < 20) {
      const int b = thr - 16;
      float h[32];
#pragma unroll
      for (int jj = 0; jj < 32; ++jj) {
        float acc = b1[jj];
        for (int i = 0; i < 8; ++i) acc += ef[b * 8 + i] * w1[i * 32 + jj];
        h[jj] = fmaxf(acc, 0.f);
      }
      float lg[5];
#pragma unroll
      for (int k = 0; k < 5; ++k) {
        float acc = b2[k];
        for (int jj = 0; jj < 32; ++jj) acc += h[jj] * w2[jj * 5 + k];
        lg[k] = 1.f / (1.f + expf(-acc));   // sigmoid
      }
      float m = lg[0];
      for (int k = 1; k < 5; ++k) m = fmaxf(m, lg[k]);
      float e5[5], es = 0.f;
      for (int k = 0; k < 5; ++k) { e5[k] = expf(lg[k] - m); es += e5[k]; }
      const float kk[5] = {3.f, 6.f, 12.f, 24.f, 48.f};
      for (int k = 0; k < 5; ++k) COEF[b * 8 + k] = (e5[k] / es) / kk[k];
    }
    __syncthreads();
    for (int idx = thr; idx < NB * TT; idx += 256) {
      int b = idx / TT, t = idx - b * TT;
      IMP[idx] = sE[b][t] + sE[4 + b][t] + sE[8 + b][t];
    }
  }
}

// ---------------- mix: u = (A+I)x -> d_out, z = Bx -> ws ---------------------
__global__ __launch_bounds__(256, 4)
void mix_kernel(const float* __restrict__ x, const float* __restrict__ fw,
                float* __restrict__ u_out, float* __restrict__ z_out) {
  __shared__ float sA[32][32];   // sA[c][o] = fw[o][c] + (o==c)
  __shared__ float sB[32][32];   // sB[c][o] = fw[o][32+c]
  const int bid = blockIdx.x, thr = threadIdx.x;
  const int b = bid / (TT * 2);
  const int r = bid - b * (TT * 2);
  const int t = r >> 1, vh = r & 1;
  const int v = vh * 256 + thr;

  {
    // 2048 fw values, 256 threads -> 8 each; split so both halves issue早 as
    // independent dwordx4-able reads
    int j0 = thr;                      // [0,256)   -> o 0..3
    int j1 = thr + 1792;               // [1792,2048) -> o 28..31
#pragma unroll
    for (int step = 0; step < 4; ++step) {
      int j = j0 + step * 512;         // covers [0,2048) in 4 strided chunks x2
      int o = j >> 6, cc = j & 63;
      float val = fw[j];
      if (cc < 32) sA[cc][o] = val + ((o == cc) ? 1.f : 0.f);
      else         sB[cc - 32][o] = val;
      int jj = j1 - step * 512;
      int o2 = jj >> 6, cc2 = jj & 63;
      float val2 = fw[jj];
      if (cc2 < 32) sA[cc2][o2] = val2 + ((o2 == cc2) ? 1.f : 0.f);
      else          sB[cc2 - 32][o2] = val2;
    }
  }
  __syncthreads();

  float u[32], z[32];
#pragma unroll
  for (int o = 0; o < 32; ++o) { u[o] = 0.f; z[o] = 0.f; }

  const size_t pbase = ((size_t)b * NC * TT + t) * VV + v;   // (b, c=0, t, v)
#pragma unroll 4
  for (int c = 0; c < 32; ++c) {
    float xv = x[pbase + (size_t)c * TT * VV];
    const float* rA = &sA[c][0];
    const float* rB = &sB[c][0];
#pragma unroll
    for (int o = 0; o < 32; o += 4) {
      float4 a4 = *(const float4*)(rA + o);
      float4 b4 = *(const float4*)(rB + o);
      u[o + 0] += a4.x * xv;  z[o + 0] += b4.x * xv;
      u[o + 1] += a4.y * xv;  z[o + 1] += b4.y * xv;
      u[o + 2] += a4.z * xv;  z[o + 2] += b4.z * xv;
      u[o + 3] += a4.w * xv;  z[o + 3] += b4.w * xv;
    }
  }
#pragma unroll
  for (int o = 0; o < 32; ++o) {
    u_out[pbase + (size_t)o * TT * VV] = u[o];
    z_out[pbase + (size_t)o * TT * VV] = z[o];
  }
}

// ---------------- trend: sliding windows over z + epilogue (in-place on d_out)
__global__ __launch_bounds__(256)
void trend_kernel(const float* __restrict__ ws_ro, float* __restrict__ uo,
                  const float* __restrict__ fb) {
  const float* Z    = ws_ro + Z_OFF;
  const float* CVp  = ws_ro + CV_OFF;
  const float* IMP  = ws_ro + IMP_OFF;
  const float* COEF = ws_ro + COEF_OFF;
  __shared__ float zL[TT * 64];
  __shared__ float impL[TT];

  const int bid = blockIdx.x, thr = threadIdx.x;
  const int b = bid >> 8, o = (bid >> 3) & 31, vt = bid & 7;
  const int v0 = vt * 64;
  const size_t zbase = (size_t)(b * NC + o) * TT * VV + v0;

  // stage z[b,o,:,v0:v0+64] (73.7 KB) + imp row
  for (int i = thr; i < TT * 16; i += 256) {
    int row = i >> 4, q = i & 15;
    float4 val = *(const float4*)(Z + zbase + (size_t)row * VV + q * 4);
    *(float4*)(&zL[row * 64 + q * 4]) = val;
  }
  for (int i = thr; i < TT; i += 256) impL[i] = IMP[b * TT + i];
  __syncthreads();

  const float ci0 = COEF[b * 8 + 0], ci1 = COEF[b * 8 + 1], ci2 = COEF[b * 8 + 2];
  const float ci3 = COEF[b * 8 + 3], ci4 = COEF[b * 8 + 4];
  const float fbv = fb[o];

  const int vl = thr & 63, strip = thr >> 6;
  const int ts = strip * 72;

  // windows: k={3,6,12,24,48}, p=k/2, covers [t-p, t+k-1-p];  p={1,3,6,12,24}
  float s0 = 0.f, s1 = 0.f, s2 = 0.f, s3 = 0.f, s4 = 0.f;
  for (int s = (ts >= 1  ? ts - 1  : 0); s <= ts + 1;  ++s) s0 += zL[s * 64 + vl];
  for (int s = (ts >= 3  ? ts - 3  : 0); s <= ts + 2;  ++s) s1 += zL[s * 64 + vl];
  for (int s = (ts >= 6  ? ts - 6  : 0); s <= ts + 5;  ++s) s2 += zL[s * 64 + vl];
  for (int s = (ts >= 12 ? ts - 12 : 0); s <= ts + 11; ++s) s3 += zL[s * 64 + vl];
  for (int s = (ts >= 24 ? ts - 24 : 0); s <= ts + 23; ++s) s4 += zL[s * 64 + vl];

  const size_t gbase  = (size_t)(b * NC + o) * TT * VV + v0 + vl;
  const size_t cvbase = (size_t)b * TT * VV + v0 + vl;

#pragma unroll 4
  for (int k = 0; k < 72; ++k) {
    const int t = ts + k;
    float comb = ci0 * s0 + ci1 * s1 + ci2 * s2 + ci3 * s3 + ci4 * s4;
    const size_t ga = gbase + (size_t)t * VV;
    float uv  = uo[ga];
    float cvv = CVp[cvbase + (size_t)t * VV];
    uo[ga] = (uv + comb + fbv) * (1.f + cvv) + impL[t];
    // slide t -> t+1 (conditions are wave-uniform: t uniform per strip)
    if (t + 2 <= TT - 1)  s0 += zL[(t + 2) * 64 + vl];
    if (t - 1 >= 0)       s0 -= zL[(t - 1) * 64 + vl];
    if (t + 3 <= TT - 1)  s1 += zL[(t + 3) * 64 + vl];
    if (t - 3 >= 0)       s1 -= zL[(t - 3) * 64 + vl];
    if (t + 6 <= TT - 1)  s2 += zL[(t + 6) * 64 + vl];
    if (t - 6 >= 0)       s2 -= zL[(t - 6) * 64 + vl];
    if (t + 12 <= TT - 1) s3 += zL[(t + 12) * 64 + vl];
    if (t - 12 >= 0)      s3 -= zL[(t - 12) * 64 + vl];
    if (t + 24 <= TT - 1) s4 += zL[(t + 24) * 64 + vl];
    if (t - 24 >= 0)      s4 -= zL[(t - 24) * 64 + vl];
  }
}

extern "C" void kernel_launch(void* const* d_in, const int* in_sizes, int n_in,
                              void* d_out, int out_size, void* d_ws, size_t ws_size,
                              hipStream_t stream) {
  if (ws_size < WS_NEED * sizeof(float)) return;  // clean fail, no OOB writes

  const float* flow = (const float*)d_in[0];
  const float* ev   = (const float*)d_in[1];
  const float* x    = (const float*)d_in[2];
  const float* ef   = (const float*)d_in[3];
  const float* w1   = (const float*)d_in[4];
  const float* b1   = (const float*)d_in[5];
  const float* w2   = (const float*)d_in[6];
  const float* b2   = (const float*)d_in[7];
  const float* fw   = (const float*)d_in[8];
  const float* fb   = (const float*)d_in[9];
  float* ws  = (float*)d_ws;
  float* out = (float*)d_out;

  prep2_kernel<<<33, 256, 0, stream>>>(flow, ev, ef, w1, b1, w2, b2, ws);
  mix_kernel<<<NB * TT * 2, 256, 0, stream>>>(x, fw, out, ws + Z_OFF);
  trend_kernel<<<NB * NC * 8, 256, 0, stream>>>(ws, out, fb);
}

// Round 5
// 374.176 us; speedup vs baseline: 1.0815x; 1.0815x over previous
//
#include <hip/hip_runtime.h>
#include <math.h>

#define TT 288
#define VV 512
#define NC 32
#define NB 4

// ws layout (floats): Z | CV | IMP | COEF   (u lives in d_out between pass1/pass2)
static constexpr size_t Z_OFF    = 0;
static constexpr size_t CV_OFF   = (size_t)NB * NC * TT * VV;      // 18,874,368
static constexpr size_t IMP_OFF  = CV_OFF + (size_t)NB * TT * VV;  // +589,824
static constexpr size_t COEF_OFF = IMP_OFF + (size_t)NB * TT;      // +1,152
static constexpr size_t WS_NEED  = COEF_OFF + (size_t)NB * 8;      // ~77.9 MB

// ---------------- prep2: rolling CV (t-seg 24) + impact scan + gate MLP ------
__global__ __launch_bounds__(256)
void prep2_kernel(const float* __restrict__ flow, const float* __restrict__ events,
                  const float* __restrict__ ef, const float* __restrict__ w1,
                  const float* __restrict__ b1, const float* __restrict__ w2,
                  const float* __restrict__ b2, float* __restrict__ ws) {
  __shared__ float sE[12][TT];
  float* CVp  = ws + CV_OFF;
  float* IMP  = ws + IMP_OFF;
  float* COEF = ws + COEF_OFF;
  const int blk = blockIdx.x, thr = threadIdx.x;

  if (blk < 96) {
    // CV: block = (b, tseg of 24, v-half); warm up 59 rows then slide
    const int b = blk / 24, r = blk % 24, tseg = r >> 1, vh = r & 1;
    const int v = vh * 256 + thr, ts = tseg * 24;
    const size_t base = (size_t)b * TT * VV + v;
    const int start = (ts >= 59) ? ts - 59 : 0;
    float s = 0.f, s2 = 0.f;
    for (int t = start; t < ts + 24; ++t) {
      float f = flow[base + (size_t)t * VV];
      s += f; s2 += f * f;
      if (t >= ts) {
        float cvv = 0.f;
        if (t >= 59) {
          float mean = s * (1.f / 60.f);
          float var  = (s2 - 60.f * mean * mean) * (1.f / 59.f);
          cvv = sqrtf(fmaxf(var, 0.f)) / (mean + 1e-6f);
        }
        CVp[base + (size_t)t * VV] = cvv;
      }
      if (t >= 59 && t - 59 >= start) {
        float fo = flow[base + (size_t)(t - 59) * VV];
        s -= fo; s2 -= fo * fo;
      }
    }
  } else {
    // impact: 12 threads = (e,b) parallel scans; gate MLP on threads 16..19
    if (thr < 12) {
      const int b = thr & 3, e = thr >> 2;
      const float r = (e == 0) ? expf(-1.f / 300.f) : (e == 1) ? expf(-1.f / 600.f) : expf(-1.f / 180.f);
      const float a = (e == 0) ? 0.3f : (e == 1) ? 0.5f : 0.2f;
      float c = 0.f;
#pragma unroll 4
      for (int t = TT - 1; t >= 0; --t) {
        c = events[((size_t)b * TT + t) * 3 + e] + r * c;
        sE[thr][t] = a * c;
      }
    } else if (thr >= 16 && thr < 20) {
      const int b = thr - 16;
      float h[32];
#pragma unroll
      for (int jj = 0; jj < 32; ++jj) {
        float acc = b1[jj];
        for (int i = 0; i < 8; ++i) acc += ef[b * 8 + i] * w1[i * 32 + jj];
        h[jj] = fmaxf(acc, 0.f);
      }
      float lg[5];
#pragma unroll
      for (int k = 0; k < 5; ++k) {
        float acc = b2[k];
        for (int jj = 0; jj < 32; ++jj) acc += h[jj] * w2[jj * 5 + k];
        lg[k] = 1.f / (1.f + expf(-acc));   // sigmoid
      }
      float m = lg[0];
      for (int k = 1; k < 5; ++k) m = fmaxf(m, lg[k]);
      float e5[5], es = 0.f;
      for (int k = 0; k < 5; ++k) { e5[k] = expf(lg[k] - m); es += e5[k]; }
      const float kk[5] = {3.f, 6.f, 12.f, 24.f, 48.f};
      for (int k = 0; k < 5; ++k) COEF[b * 8 + k] = (e5[k] / es) / kk[k];
    }
    __syncthreads();
    for (int idx = thr; idx < NB * TT; idx += 256) {
      int b = idx / TT, t = idx - b * TT;
      IMP[idx] = sE[b][t] + sE[4 + b][t] + sE[8 + b][t];
    }
  }
}

// ---------------- mix2: o-split halves; u -> d_out, z -> ws ------------------
__global__ __launch_bounds__(256, 4)
void mix2_kernel(const float* __restrict__ x, const float* __restrict__ fw,
                 float* __restrict__ u_out, float* __restrict__ z_out) {
  __shared__ float sA[32][16];   // sA[c][ol] = fw[o][c] + (o==c), o = oh*16+ol
  __shared__ float sB[32][16];   // sB[c][ol] = fw[o][32+c]
  int r = blockIdx.x;
  const int oh = r & 1;  r >>= 1;
  const int vh = r & 1;  r >>= 1;
  const int t  = r % TT;
  const int b  = r / TT;
  const int thr = threadIdx.x;
  const int v = vh * 256 + thr;

  // stage 1024 fw values (rows o in [oh*16, oh*16+16), cols 0..63)
#pragma unroll
  for (int step = 0; step < 4; ++step) {
    int j  = thr + step * 256;          // [0,1024)
    int ol = j >> 6, cc = j & 63;
    int o  = oh * 16 + ol;
    float val = fw[o * 64 + cc];
    if (cc < 32) sA[cc][ol] = val + ((o == cc) ? 1.f : 0.f);
    else         sB[cc - 32][ol] = val;
  }
  __syncthreads();

  float u[16], z[16];
#pragma unroll
  for (int ol = 0; ol < 16; ++ol) { u[ol] = 0.f; z[ol] = 0.f; }

  const size_t pbase = ((size_t)b * NC * TT + t) * VV + v;   // (b, c=0, t, v)
#pragma unroll 4
  for (int c = 0; c < 32; ++c) {
    float xv = x[pbase + (size_t)c * TT * VV];
    const float* rA = &sA[c][0];
    const float* rB = &sB[c][0];
#pragma unroll
    for (int ol = 0; ol < 16; ol += 4) {
      float4 a4 = *(const float4*)(rA + ol);
      float4 b4 = *(const float4*)(rB + ol);
      u[ol + 0] += a4.x * xv;  z[ol + 0] += b4.x * xv;
      u[ol + 1] += a4.y * xv;  z[ol + 1] += b4.y * xv;
      u[ol + 2] += a4.z * xv;  z[ol + 2] += b4.z * xv;
      u[ol + 3] += a4.w * xv;  z[ol + 3] += b4.w * xv;
    }
  }
#pragma unroll
  for (int ol = 0; ol < 16; ++ol) {
    size_t oa = pbase + (size_t)(oh * 16 + ol) * TT * VV;
    u_out[oa] = u[ol];
    z_out[oa] = z[ol];
  }
}

// ---------------- trend2: no-LDS sliding windows, epilogue in-place on d_out -
__global__ __launch_bounds__(256, 6)
void trend2_kernel(const float* __restrict__ ws_ro, float* __restrict__ uo,
                   const float* __restrict__ fb) {
  const float* Z    = ws_ro + Z_OFF;
  const float* CVp  = ws_ro + CV_OFF;
  const float* IMP  = ws_ro + IMP_OFF;
  const float* COEF = ws_ro + COEF_OFF;

  int r = blockIdx.x;                 // 2048 = b(4) x o(32) x vh(2) x strip(8)
  const int strip = r & 7;  r >>= 3;
  const int vh    = r & 1;  r >>= 1;
  const int o     = r & 31; r >>= 5;
  const int b     = r;
  const int thr = threadIdx.x;
  const int v = vh * 256 + thr;
  const int ts = strip * 36;

  const float* zb  = Z   + (size_t)(b * NC + o) * TT * VV + v;
  float*       ub  = uo  + (size_t)(b * NC + o) * TT * VV + v;
  const float* cvb = CVp + (size_t)b * TT * VV + v;
  const float* ib  = IMP + b * TT;

  const float ci0 = COEF[b * 8 + 0], ci1 = COEF[b * 8 + 1], ci2 = COEF[b * 8 + 2];
  const float ci3 = COEF[b * 8 + 3], ci4 = COEF[b * 8 + 4];
  const float fbv = fb[o];

  // warm-up: one pass over [ts-24, ts+23] feeding all 5 nested windows
  // windows at t: k=3:[t-1,t+1] 6:[t-3,t+2] 12:[t-6,t+5] 24:[t-12,t+11] 48:[t-24,t+23]
  float s0 = 0.f, s1 = 0.f, s2 = 0.f, s3 = 0.f, s4 = 0.f;
  {
    const int lo = (ts >= 24) ? ts - 24 : 0;
    for (int s = lo; s <= ts + 23; ++s) {     // ts+23 <= 275, no upper clamp
      float zv = zb[s * VV];
      int d = s - ts;
      s4 += zv;
      if (d >= -12 && d <= 11) s3 += zv;
      if (d >= -6  && d <= 5)  s2 += zv;
      if (d >= -3  && d <= 2)  s1 += zv;
      if (d >= -1  && d <= 1)  s0 += zv;
    }
  }

#pragma unroll 4
  for (int k = 0; k < 36; ++k) {
    const int t = ts + k;
    float comb = ci0 * s0 + ci1 * s1 + ci2 * s2 + ci3 * s3 + ci4 * s4;
    float uv  = ub[t * VV];
    float cvv = cvb[t * VV];
    float im  = ib[t];
    ub[t * VV] = (uv + comb + fbv) * (1.f + cvv) + im;
    // slide t -> t+1 (all conditions wave-uniform)
    if (t + 2  <= TT - 1) s0 += zb[(t + 2)  * VV];
    if (t - 1  >= 0)      s0 -= zb[(t - 1)  * VV];
    if (t + 3  <= TT - 1) s1 += zb[(t + 3)  * VV];
    if (t - 3  >= 0)      s1 -= zb[(t - 3)  * VV];
    if (t + 6  <= TT - 1) s2 += zb[(t + 6)  * VV];
    if (t - 6  >= 0)      s2 -= zb[(t - 6)  * VV];
    if (t + 12 <= TT - 1) s3 += zb[(t + 12) * VV];
    if (t - 12 >= 0)      s3 -= zb[(t - 12) * VV];
    if (t + 24 <= TT - 1) s4 += zb[(t + 24) * VV];
    if (t - 24 >= 0)      s4 -= zb[(t - 24) * VV];
  }
}

extern "C" void kernel_launch(void* const* d_in, const int* in_sizes, int n_in,
                              void* d_out, int out_size, void* d_ws, size_t ws_size,
                              hipStream_t stream) {
  if (ws_size < WS_NEED * sizeof(float)) return;  // clean fail, no OOB writes

  const float* flow = (const float*)d_in[0];
  const float* ev   = (const float*)d_in[1];
  const float* x    = (const float*)d_in[2];
  const float* ef   = (const float*)d_in[3];
  const float* w1   = (const float*)d_in[4];
  const float* b1   = (const float*)d_in[5];
  const float* w2   = (const float*)d_in[6];
  const float* b2   = (const float*)d_in[7];
  const float* fw   = (const float*)d_in[8];
  const float* fb   = (const float*)d_in[9];
  float* ws  = (float*)d_ws;
  float* out = (float*)d_out;

  prep2_kernel<<<97, 256, 0, stream>>>(flow, ev, ef, w1, b1, w2, b2, ws);
  mix2_kernel<<<NB * TT * 4, 256, 0, stream>>>(x, fw, out, ws + Z_OFF);
  trend2_kernel<<<NB * NC * 2 * 8, 256, 0, stream>>>(ws, out, fb);
}

// Round 6
// 251.399 us; speedup vs baseline: 1.6096x; 1.4884x over previous
//
#include <hip/hip_runtime.h>
#include <math.h>

#define TT 288
#define VV 512
#define NC 32
#define NB 4

// ws layout (floats): Z | CV | IMP | COEF   (u lives in d_out between pass1/pass2)
static constexpr size_t Z_OFF    = 0;
static constexpr size_t CV_OFF   = (size_t)NB * NC * TT * VV;      // 18,874,368
static constexpr size_t IMP_OFF  = CV_OFF + (size_t)NB * TT * VV;  // +589,824
static constexpr size_t COEF_OFF = IMP_OFF + (size_t)NB * TT;      // +1,152
static constexpr size_t WS_NEED  = COEF_OFF + (size_t)NB * 8;      // ~77.9 MB

// ---- mixprep: blocks 0..95 CV, block 96 impact+gate, blocks 97+ mix (o-split)
__global__ __launch_bounds__(256, 4)
void mixprep_kernel(const float* __restrict__ flow, const float* __restrict__ events,
                    const float* __restrict__ ef, const float* __restrict__ w1,
                    const float* __restrict__ b1, const float* __restrict__ w2,
                    const float* __restrict__ b2, const float* __restrict__ x,
                    const float* __restrict__ fw, float* __restrict__ u_out,
                    float* __restrict__ ws) {
  __shared__ float sE[12][TT];   // impact block only
  __shared__ float sA[32][16];   // mix blocks only
  __shared__ float sB[32][16];
  float* CVp  = ws + CV_OFF;
  float* IMP  = ws + IMP_OFF;
  float* COEF = ws + COEF_OFF;
  float* z_out = ws + Z_OFF;
  const int blk = blockIdx.x, thr = threadIdx.x;

  if (blk < 96) {
    // CV: block = (b, tseg of 24, v-half); warm up 59 rows then slide
    const int b = blk / 24, r = blk % 24, tseg = r >> 1, vh = r & 1;
    const int v = vh * 256 + thr, ts = tseg * 24;
    const size_t base = (size_t)b * TT * VV + v;
    const int start = (ts >= 59) ? ts - 59 : 0;
    float s = 0.f, s2 = 0.f;
    for (int t = start; t < ts + 24; ++t) {
      float f = flow[base + (size_t)t * VV];
      s += f; s2 += f * f;
      if (t >= ts) {
        float cvv = 0.f;
        if (t >= 59) {
          float mean = s * (1.f / 60.f);
          float var  = (s2 - 60.f * mean * mean) * (1.f / 59.f);
          cvv = sqrtf(fmaxf(var, 0.f)) / (mean + 1e-6f);
        }
        CVp[base + (size_t)t * VV] = cvv;
      }
      if (t >= 59 && t - 59 >= start) {
        float fo = flow[base + (size_t)(t - 59) * VV];
        s -= fo; s2 -= fo * fo;
      }
    }
  } else if (blk == 96) {
    // impact: 12 threads = (e,b) parallel scans; gate MLP on threads 16..19
    if (thr < 12) {
      const int b = thr & 3, e = thr >> 2;
      const float r = (e == 0) ? expf(-1.f / 300.f) : (e == 1) ? expf(-1.f / 600.f) : expf(-1.f / 180.f);
      const float a = (e == 0) ? 0.3f : (e == 1) ? 0.5f : 0.2f;
      float c = 0.f;
#pragma unroll 4
      for (int t = TT - 1; t >= 0; --t) {
        c = events[((size_t)b * TT + t) * 3 + e] + r * c;
        sE[thr][t] = a * c;
      }
    } else if (thr >= 16 && thr < 20) {
      const int b = thr - 16;
      float h[32];
#pragma unroll
      for (int jj = 0; jj < 32; ++jj) {
        float acc = b1[jj];
        for (int i = 0; i < 8; ++i) acc += ef[b * 8 + i] * w1[i * 32 + jj];
        h[jj] = fmaxf(acc, 0.f);
      }
      float lg[5];
#pragma unroll
      for (int k = 0; k < 5; ++k) {
        float acc = b2[k];
        for (int jj = 0; jj < 32; ++jj) acc += h[jj] * w2[jj * 5 + k];
        lg[k] = 1.f / (1.f + expf(-acc));   // sigmoid
      }
      float m = lg[0];
      for (int k = 1; k < 5; ++k) m = fmaxf(m, lg[k]);
      float e5[5], es = 0.f;
      for (int k = 0; k < 5; ++k) { e5[k] = expf(lg[k] - m); es += e5[k]; }
      const float kk[5] = {3.f, 6.f, 12.f, 24.f, 48.f};
      for (int k = 0; k < 5; ++k) COEF[b * 8 + k] = (e5[k] / es) / kk[k];
    }
    __syncthreads();
    for (int idx = thr; idx < NB * TT; idx += 256) {
      int b = idx / TT, t = idx - b * TT;
      IMP[idx] = sE[b][t] + sE[4 + b][t] + sE[8 + b][t];
    }
  } else {
    // ---- mix: u = (A+I)x -> d_out, z = Bx -> ws; o split in halves ----
    int r = blk - 97;
    const int oh = r & 1;  r >>= 1;
    const int vh = r & 1;  r >>= 1;
    const int t  = r % TT;
    const int b  = r / TT;
    const int v = vh * 256 + thr;

#pragma unroll
    for (int step = 0; step < 4; ++step) {
      int j  = thr + step * 256;          // [0,1024)
      int ol = j >> 6, cc = j & 63;
      int o  = oh * 16 + ol;
      float val = fw[o * 64 + cc];
      if (cc < 32) sA[cc][ol] = val + ((o == cc) ? 1.f : 0.f);
      else         sB[cc - 32][ol] = val;
    }
    __syncthreads();

    float u[16], z[16];
#pragma unroll
    for (int ol = 0; ol < 16; ++ol) { u[ol] = 0.f; z[ol] = 0.f; }

    const size_t pbase = ((size_t)b * NC * TT + t) * VV + v;   // (b, c=0, t, v)
#pragma unroll 4
    for (int c = 0; c < 32; ++c) {
      float xv = x[pbase + (size_t)c * TT * VV];
      const float* rA = &sA[c][0];
      const float* rB = &sB[c][0];
#pragma unroll
      for (int ol = 0; ol < 16; ol += 4) {
        float4 a4 = *(const float4*)(rA + ol);
        float4 b4 = *(const float4*)(rB + ol);
        u[ol + 0] += a4.x * xv;  z[ol + 0] += b4.x * xv;
        u[ol + 1] += a4.y * xv;  z[ol + 1] += b4.y * xv;
        u[ol + 2] += a4.z * xv;  z[ol + 2] += b4.z * xv;
        u[ol + 3] += a4.w * xv;  z[ol + 3] += b4.w * xv;
      }
    }
#pragma unroll
    for (int ol = 0; ol < 16; ++ol) {
      size_t oa = pbase + (size_t)(oh * 16 + ol) * TT * VV;
      u_out[oa] = u[ol];
      z_out[oa] = z[ol];
    }
  }
}

// ---- trend3: per-thread 48-deep register ring; 1 z load per output step -----
// slot(z[ts+m]) = (m-24) mod 48; tap at t+c (t=ts+k) -> slot (k+c+24) mod 48
__global__ __launch_bounds__(256)
void trend3_kernel(const float* __restrict__ ws_ro, float* __restrict__ uo,
                   const float* __restrict__ fb) {
  const float* Z    = ws_ro + Z_OFF;
  const float* CVp  = ws_ro + CV_OFF;
  const float* IMP  = ws_ro + IMP_OFF;
  const float* COEF = ws_ro + COEF_OFF;

  int r = blockIdx.x;                 // 1024 = b(4) x o(32) x vh(2) x strip(4)
  const int strip = r & 3;  r >>= 2;
  const int vh    = r & 1;  r >>= 1;
  const int o     = r & 31; r >>= 5;
  const int b     = r;
  const int thr = threadIdx.x;
  const int v = vh * 256 + thr;
  const int ts = strip * 72;

  const float* zb  = Z   + (size_t)(b * NC + o) * TT * VV + v;
  float*       ub  = uo  + (size_t)(b * NC + o) * TT * VV + v;
  const float* cvb = CVp + (size_t)b * TT * VV + v;
  const float* ib  = IMP + b * TT;

  const float ci0 = COEF[b * 8 + 0], ci1 = COEF[b * 8 + 1], ci2 = COEF[b * 8 + 2];
  const float ci3 = COEF[b * 8 + 3], ci4 = COEF[b * 8 + 4];
  const float fbv = fb[o];

  // preload ring[i] = z[ts-24+i], i=0..47 (0 if OOB; ts+23 <= 239 so no hi clamp)
  float ring[48];
#pragma unroll
  for (int i = 0; i < 48; ++i) {
    int t = ts - 24 + i;
    ring[i] = (t >= 0) ? zb[t * VV] : 0.f;
  }

  // warm-up sums at t=ts: windows map to static slot ranges
  // s0:[t-1,t+1]->23..25  s1:[t-3,t+2]->21..26  s2:[t-6,t+5]->18..29
  // s3:[t-12,t+11]->12..35  s4:[t-24,t+23]->0..47
  float s0 = 0.f, s1 = 0.f, s2 = 0.f, s3 = 0.f, s4 = 0.f;
#pragma unroll
  for (int i = 0; i < 48; ++i) {
    float zv = ring[i];
    s4 += zv;
    if (i >= 12 && i <= 35) s3 += zv;
    if (i >= 18 && i <= 29) s2 += zv;
    if (i >= 21 && i <= 26) s1 += zv;
    if (i >= 23 && i <= 25) s0 += zv;
  }

#pragma unroll
  for (int k = 0; k < 72; ++k) {
    const int t = ts + k;
    // output at t with current sums
    float comb = ci0 * s0 + ci1 * s1 + ci2 * s2 + ci3 * s3 + ci4 * s4;
    float uv  = ub[t * VV];
    float cvv = cvb[t * VV];
    ub[t * VV] = (uv + comb + fbv) * (1.f + cvv) + ib[t];

    // slide t -> t+1. OOB slots hold 0 so adds/subs are unconditional.
    s0 -= ring[(k + 23) % 48];          // z[t-1]
    s1 -= ring[(k + 21) % 48];          // z[t-3]
    s2 -= ring[(k + 18) % 48];          // z[t-6]
    s3 -= ring[(k + 12) % 48];          // z[t-12]
    s4 -= ring[(k +  0) % 48];          // z[t-24]
    float zn;
    if (t + 24 <= TT - 1) zn = zb[(t + 24) * VV];  // block-uniform branch
    else                  zn = 0.f;
    s0 += ring[(k + 26) % 48];          // z[t+2]
    s1 += ring[(k + 27) % 48];          // z[t+3]
    s2 += ring[(k + 30) % 48];          // z[t+6]
    s3 += ring[(k + 36) % 48];          // z[t+12]
    s4 += zn;                           // z[t+24]
    ring[k % 48] = zn;
  }
}

extern "C" void kernel_launch(void* const* d_in, const int* in_sizes, int n_in,
                              void* d_out, int out_size, void* d_ws, size_t ws_size,
                              hipStream_t stream) {
  if (ws_size < WS_NEED * sizeof(float)) return;  // clean fail, no OOB writes

  const float* flow = (const float*)d_in[0];
  const float* ev   = (const float*)d_in[1];
  const float* x    = (const float*)d_in[2];
  const float* ef   = (const float*)d_in[3];
  const float* w1   = (const float*)d_in[4];
  const float* b1   = (const float*)d_in[5];
  const float* w2   = (const float*)d_in[6];
  const float* b2   = (const float*)d_in[7];
  const float* fw   = (const float*)d_in[8];
  const float* fb   = (const float*)d_in[9];
  float* ws  = (float*)d_ws;
  float* out = (float*)d_out;

  mixprep_kernel<<<97 + NB * TT * 4, 256, 0, stream>>>(flow, ev, ef, w1, b1, w2, b2,
                                                       x, fw, out, ws);
  trend3_kernel<<<NB * NC * 2 * 4, 256, 0, stream>>>(ws, out, fb);
}